// Round 2
// baseline (88.787 us; speedup 1.0000x reference)
//
#include <hip/hip_runtime.h>
#include <math.h>

#define HH 256
#define WW 256
#define CC 8
#define KK 25
#define ND 9
#define NB 2

__global__ __launch_bounds__(256) void cost_kernel(
    const float* __restrict__ fm,    // [B][C][K][H][W]
    const float* __restrict__ mask,  // [B][K][H][W]
    const float* __restrict__ wgt,   // [C][K]
    float* __restrict__ out)         // [B][C][ND][H][W]
{
#pragma clang fp contract(off)
    const int j = threadIdx.x;            // 0..255 (column)
    int bi = blockIdx.x;
    const int i = bi & 255; bi >>= 8;     // row
    const int c = bi & 7;  bi >>= 3;      // channel
    const int b = bi;                      // batch

    const float* fmb = fm + (size_t)(b * CC + c) * KK * (HH * WW);
    const float* mb  = mask + (size_t)b * KK * (HH * WW);

    float acc[ND];
#pragma unroll
    for (int dd = 0; dd < ND; ++dd) acc[dd] = 0.f;
    float msum = 0.f;

    // Strict sequential k accumulation, separate mul/add (numpy einsum order):
    //   p = f*m (rounded); t = p*w (rounded); acc = acc + t (rounded)
    for (int k = 0; k < KK; ++k) {
        const int du = k / 5 - 2;
        const int dv = k % 5 - 2;
        const float mk = mb[(size_t)k * HH * WW + i * WW + j];
        msum = __fadd_rn(msum, mk);
        const float wk = wgt[c * KK + k];
        const float* fp = fmb + (size_t)k * HH * WW;
#pragma unroll
        for (int dd = 0; dd < ND; ++dd) {
            const int d = dd - 4;
            const int y = i - du * d;
            const int x = j - dv * d;
            float f = 0.f;
            if ((unsigned)y < HH && (unsigned)x < WW)
                f = fp[y * WW + x];
            const float p = __fmul_rn(f, mk);     // mod = shifted * mask
            const float t = __fmul_rn(p, wk);     // * weight
            acc[dd] = __fadd_rn(acc[dd], t);      // sequential sum over k
        }
    }

    const float mavg = __fdiv_rn(msum, 25.0f);    // np.mean: sum / n
    float* ob = out + (size_t)(b * CC + c) * ND * (HH * WW);
#pragma unroll
    for (int dd = 0; dd < ND; ++dd) {
        ob[((size_t)dd * HH + i) * WW + j] = floorf(__fdiv_rn(acc[dd], mavg));
    }
}

extern "C" void kernel_launch(void* const* d_in, const int* in_sizes, int n_in,
                              void* d_out, int out_size, void* d_ws, size_t ws_size,
                              hipStream_t stream) {
    const float* fm   = (const float*)d_in[0];
    const float* mask = (const float*)d_in[1];
    const float* wgt  = (const float*)d_in[2];
    float* out = (float*)d_out;

    dim3 grid(NB * CC * HH);   // 4096 blocks: (b, c, row)
    dim3 block(WW);            // 256 threads: one column each
    cost_kernel<<<grid, block, 0, stream>>>(fm, mask, wgt, out);
}